// Round 8
// baseline (389.837 us; speedup 1.0000x reference)
//
#include <hip/hip_runtime.h>
#include <hip/hip_bf16.h>

typedef __attribute__((ext_vector_type(8))) short short8;
typedef __attribute__((ext_vector_type(8))) unsigned short ushort8;
typedef __attribute__((ext_vector_type(4))) float f32x4;

typedef const __attribute__((address_space(1))) void* as1cv_t;
typedef __attribute__((address_space(3))) void* as3v_t;
typedef __attribute__((address_space(3))) const char* as3cc_t;
typedef __attribute__((address_space(3))) const short8* as3s8_t;

__device__ __forceinline__ unsigned short f2bf(float f) {
    unsigned u = __float_as_uint(f);
    u += 0x7fffu + ((u >> 16) & 1u);   // round-to-nearest-even
    return (unsigned short)(u >> 16);
}

__device__ __forceinline__ float gelu_tanh_f(float x) {
    float t = 0.7978845608028654f * (x + 0.044715f * x * x * x);
    float u = 2.0f * t;
    u = fminf(fmaxf(u, -30.0f), 30.0f);
    float e = __expf(u);
    float th = (e - 1.0f) / (e + 1.0f);
    return 0.5f * x * (1.0f + th);
}

// ---------------- conversion: fp32 -> bf16, elementwise ----------------
__global__ void cvt_f32_to_bf16(const float* __restrict__ in,
                                unsigned short* __restrict__ out,
                                long long n) {
    long long i = (long long)blockIdx.x * blockDim.x + threadIdx.x;
    long long stride = (long long)gridDim.x * blockDim.x;
    const float4* in4 = (const float4*)in;
    ushort4* out4 = (ushort4*)out;
    long long n4 = n >> 2;
    for (long long j = i; j < n4; j += stride) {
        float4 v = in4[j];
        ushort4 o;
        o.x = f2bf(v.x); o.y = f2bf(v.y); o.z = f2bf(v.z); o.w = f2bf(v.w);
        out4[j] = o;
    }
}

// ---- ROUND 8: transpose + convert, in [E][R][C] fp32 -> out [E][C][R] bf16 ----
// 64x64 tiles, 256 threads. LDS stored pre-transposed [c][r] with +1 pad:
// scatter-write on load (2-way banks = free), contiguous read + ushort8
// (16B/lane) store with 64B-contiguous lane groups. Old version had
// unaligned b128 reads (scalarized) and 8B/lane stores.
__global__ void transpose_cvt64v2(const float* __restrict__ in,
                                  unsigned short* __restrict__ out,
                                  int R, int C) {
    __shared__ float LT[64 * 65];   // [c][r], r padded to 65
    int e = blockIdx.z;
    int c0 = blockIdx.x * 64;
    int r0 = blockIdx.y * 64;
    const float* ine = in + (size_t)e * R * C;
    unsigned short* oute = out + (size_t)e * R * C;
    int t = threadIdx.x;  // 256
#pragma unroll
    for (int q = 0; q < 4; ++q) {
        int f = q * 256 + t;
        int lr = f >> 4;          // row 0..63
        int lc4 = f & 15;         // col-quad
        float4 v = *(const float4*)(ine + (size_t)(r0 + lr) * C + c0 + lc4 * 4);
        LT[(lc4 * 4 + 0) * 65 + lr] = v.x;
        LT[(lc4 * 4 + 1) * 65 + lr] = v.y;
        LT[(lc4 * 4 + 2) * 65 + lr] = v.z;
        LT[(lc4 * 4 + 3) * 65 + lr] = v.w;
    }
    __syncthreads();
#pragma unroll
    for (int s = 0; s < 2; ++s) {
        int oc = t >> 2;                  // out row (c) 0..63
        int or8 = (t & 3) + s * 4;        // out col-octet 0..7
        const float* src = &LT[oc * 65 + or8 * 8];
        ushort8 o;
#pragma unroll
        for (int j = 0; j < 8; ++j) o[j] = f2bf(src[j]);
        *(ushort8*)(oute + (size_t)(c0 + oc) * R + r0 + or8 * 8) = o;
    }
}

// =======================================================================
// GEMM: FROZEN control from round 7 (persistent 8-phase, byte-identical).
// =======================================================================
__device__ __forceinline__ void gload16(const void* g, void* l) {
    __builtin_amdgcn_global_load_lds((as1cv_t)g, (as3v_t)l, 16, 0, 0);
}

#define MFMA_BF16 __builtin_amdgcn_mfma_f32_16x16x32_bf16

template <int DO_GELU, int ROUNDS>
__device__ __forceinline__ void gemm_body(
    const unsigned short* __restrict__ A,   // [E][M][K] bf16
    const unsigned short* __restrict__ Bt,  // [E][N][K] bf16
    void* __restrict__ Cout,                // [E][M][N] bf16 (gelu) or fp32
    int M, int N, int K, int bmw_count, int per_e, int nwg)
{
    int bid = blockIdx.x;
    int gbid = (bid & 7) * (nwg >> 3) + (bid >> 3);
    int e  = gbid / per_e;
    int t0_ = gbid % per_e;
    int bn  = t0_ / bmw_count;
    int sub = t0_ % bmw_count;
    int bm0 = sub * ROUNDS;

    const size_t K2 = (size_t)K * 2;
    const char* Ae = (const char*)A  + ((size_t)e * M * K + (size_t)bm0 * 256 * K) * 2;
    const char* Be = (const char*)Bt + ((size_t)e * N * K + (size_t)bn  * 256 * K) * 2;

    __shared__ alignas(16) unsigned short lds[2 * 32768];   // 128 KiB
    char* ldsc = (char*)lds;
    as3cc_t lb = (as3cc_t)(const char*)lds;

    int tid  = threadIdx.x;
    int wid  = tid >> 6;
    int lane = tid & 63;
    int wave_m = wid >> 2;
    int wave_n = wid & 3;

    int srow = wid * 8 + (lane >> 3);
    int kbsw = ((lane & 7) ^ (srow & 7)) << 4;
    const char* gA = Ae + (size_t)srow * K2 + kbsw;
    const char* gB = Be + (size_t)srow * K2 + kbsw;
    const size_t HROW = 64 * K2;
    const size_t HALF = 128 * K2;
    int sOff = wid << 10;

    unsigned kg   = (unsigned)(lane >> 4);
    unsigned keyl = (unsigned)((lane & 15) & 7);
    unsigned sl0  = (kg ^ keyl) << 4;
    unsigned aoff = (unsigned)(wave_m * 16384 + (lane & 15) * 128) + sl0;
    unsigned boff = 32768u + (unsigned)((wave_n >> 1) * 16384 +
                    ((wave_n & 1) * 64 + (lane & 15)) * 128) + sl0;

    f32x4 acc[8][4];
    f32x4 zero = {0.0f, 0.0f, 0.0f, 0.0f};
#pragma unroll
    for (int i = 0; i < 8; i++)
#pragma unroll
        for (int j = 0; j < 4; j++) acc[i][j] = zero;

    const int KT = K >> 6;
    const int NT_TOT = ROUNDS * KT;
    const size_t AROUND = 255 * K2;

    int kA = 0, kB = 0;
#define ADV_A() do { gA += 128; if (++kA == KT) { kA = 0; gA += AROUND; } } while (0)
#define ADV_B() do { gB += 128; if (++kB == KT) { kB = 0; gB -= K2; } } while (0)

#define STG_A(h, r, bufbit) gload16(gA + (h) * HALF + (r) * HROW, \
        ldsc + ((bufbit) << 16) + (h) * 16384 + (r) * 8192 + sOff)
#define STG_B(h, r, bufbit) gload16(gB + (h) * HALF + (r) * HROW, \
        ldsc + ((bufbit) << 16) + 32768 + (h) * 16384 + (r) * 8192 + sOff)

    STG_A(0, 0, 0); STG_A(0, 1, 0); STG_A(1, 0, 0); STG_A(1, 1, 0);
    STG_B(0, 0, 0); STG_B(0, 1, 0); STG_B(1, 0, 0); STG_B(1, 1, 0);
    ADV_B();
    if (NT_TOT > 1) {
        STG_B(0, 0, 1); STG_B(0, 1, 1); STG_B(1, 0, 1); STG_B(1, 1, 1);
        asm volatile("s_waitcnt vmcnt(4)" ::: "memory");
    } else {
        asm volatile("s_waitcnt vmcnt(0)" ::: "memory");
    }
    ADV_B();
    ADV_A();
    __builtin_amdgcn_s_barrier();

    int ktEp = 0, rEp = 0;

    for (int t = 0; t < NT_TOT; ++t) {
        unsigned bufR = (unsigned)(t & 1) << 16;
        int wbA = (t + 1) & 1;
        int wbB = t & 1;
        bool stA = (t + 1) < NT_TOT;
        bool stB = (t + 2) < NT_TOT;

        unsigned pa0 = bufR + aoff, pa1 = pa0 ^ 64u;
        unsigned pb0 = bufR + boff, pb1 = pb0 ^ 64u;

        short8 aL[4][2], aH[4][2], bL[2][2], bH[2][2];

        // phase 1
#pragma unroll
        for (int mi = 0; mi < 4; ++mi) {
            aL[mi][0] = *(as3s8_t)(lb + (pa0 + mi * 2048));
            aL[mi][1] = *(as3s8_t)(lb + (pa1 + mi * 2048));
        }
#pragma unroll
        for (int ni = 0; ni < 2; ++ni) {
            bL[ni][0] = *(as3s8_t)(lb + (pb0 + ni * 2048));
            bL[ni][1] = *(as3s8_t)(lb + (pb1 + ni * 2048));
        }
        if (stA) { STG_A(0, 0, wbA); STG_A(0, 1, wbA); }
        __builtin_amdgcn_sched_barrier(0);
        __builtin_amdgcn_s_barrier();
        asm volatile("s_waitcnt lgkmcnt(0)" ::: "memory");
        __builtin_amdgcn_s_setprio(1);
#pragma unroll
        for (int ks = 0; ks < 2; ++ks)
#pragma unroll
            for (int mi = 0; mi < 4; ++mi)
#pragma unroll
                for (int ni = 0; ni < 2; ++ni)
                    acc[mi][ni] = MFMA_BF16(aL[mi][ks], bL[ni][ks], acc[mi][ni], 0, 0, 0);
        __builtin_amdgcn_s_setprio(0);
        __builtin_amdgcn_sched_barrier(0);
        __builtin_amdgcn_s_barrier();

        // phase 2
#pragma unroll
        for (int ni = 0; ni < 2; ++ni) {
            bH[ni][0] = *(as3s8_t)(lb + (pb0 + (2 + ni) * 2048));
            bH[ni][1] = *(as3s8_t)(lb + (pb1 + (2 + ni) * 2048));
        }
        if (stA) { STG_A(1, 0, wbA); STG_A(1, 1, wbA); }
        ADV_A();
        __builtin_amdgcn_sched_barrier(0);
        __builtin_amdgcn_s_barrier();
        asm volatile("s_waitcnt lgkmcnt(0)" ::: "memory");
        __builtin_amdgcn_s_setprio(1);
#pragma unroll
        for (int ks = 0; ks < 2; ++ks)
#pragma unroll
            for (int mi = 0; mi < 4; ++mi)
#pragma unroll
                for (int ni = 0; ni < 2; ++ni)
                    acc[mi][2 + ni] = MFMA_BF16(aL[mi][ks], bH[ni][ks], acc[mi][2 + ni], 0, 0, 0);
        __builtin_amdgcn_s_setprio(0);
        __builtin_amdgcn_sched_barrier(0);
        __builtin_amdgcn_s_barrier();

        // phase 3
#pragma unroll
        for (int mi = 0; mi < 4; ++mi) {
            aH[mi][0] = *(as3s8_t)(lb + (pa0 + (4 + mi) * 2048));
            aH[mi][1] = *(as3s8_t)(lb + (pa1 + (4 + mi) * 2048));
        }
        if (stB) { STG_B(0, 0, wbB); STG_B(0, 1, wbB); }
        __builtin_amdgcn_sched_barrier(0);
        __builtin_amdgcn_s_barrier();
        asm volatile("s_waitcnt lgkmcnt(0)" ::: "memory");
        __builtin_amdgcn_s_setprio(1);
#pragma unroll
        for (int ks = 0; ks < 2; ++ks)
#pragma unroll
            for (int mi = 0; mi < 4; ++mi)
#pragma unroll
                for (int ni = 0; ni < 2; ++ni)
                    acc[4 + mi][2 + ni] = MFMA_BF16(aH[mi][ks], bH[ni][ks], acc[4 + mi][2 + ni], 0, 0, 0);
        __builtin_amdgcn_s_setprio(0);
        __builtin_amdgcn_sched_barrier(0);
        __builtin_amdgcn_s_barrier();

        // phase 4
        if (stB) { STG_B(1, 0, wbB); STG_B(1, 1, wbB); }
        ADV_B();
        if (stB) asm volatile("s_waitcnt vmcnt(4)" ::: "memory");
        else     asm volatile("s_waitcnt vmcnt(0)" ::: "memory");
        __builtin_amdgcn_sched_barrier(0);
        __builtin_amdgcn_s_barrier();
        asm volatile("s_waitcnt lgkmcnt(0)" ::: "memory");
        __builtin_amdgcn_s_setprio(1);
#pragma unroll
        for (int ks = 0; ks < 2; ++ks)
#pragma unroll
            for (int mi = 0; mi < 4; ++mi)
#pragma unroll
                for (int ni = 0; ni < 2; ++ni)
                    acc[4 + mi][ni] = MFMA_BF16(aH[mi][ks], bL[ni][ks], acc[4 + mi][ni], 0, 0, 0);
        __builtin_amdgcn_s_setprio(0);
        __builtin_amdgcn_sched_barrier(0);
        __builtin_amdgcn_s_barrier();

        // per-round epilogue
        if (++ktEp == KT) {
            ktEp = 0;
            int row0 = (bm0 + rEp) * 256 + wave_m * 128 + ((lane >> 4) << 2);
            int col0 = bn * 256 + wave_n * 64 + (lane & 15);
            if (DO_GELU) {
                unsigned short* Ce = (unsigned short*)Cout + (size_t)e * M * N;
#pragma unroll
                for (int m = 0; m < 8; ++m)
#pragma unroll
                    for (int n = 0; n < 4; ++n)
#pragma unroll
                        for (int j = 0; j < 4; ++j) {
                            int row = row0 + m * 16 + j;
                            int col = col0 + n * 16;
                            Ce[(size_t)row * N + col] = f2bf(gelu_tanh_f(acc[m][n][j]));
                        }
            } else {
                float* Ce = (float*)Cout + (size_t)e * M * N;
#pragma unroll
                for (int m = 0; m < 8; ++m)
#pragma unroll
                    for (int n = 0; n < 4; ++n)
#pragma unroll
                        for (int j = 0; j < 4; ++j) {
                            int row = row0 + m * 16 + j;
                            int col = col0 + n * 16;
                            Ce[(size_t)row * N + col] = acc[m][n][j];
                        }
            }
            rEp++;
#pragma unroll
            for (int i = 0; i < 8; i++)
#pragma unroll
                for (int j = 0; j < 4; j++) acc[i][j] = zero;
        }
    }
#undef STG_A
#undef STG_B
#undef ADV_A
#undef ADV_B
}

__global__ __launch_bounds__(512, 2) void gemm_mlp1(
    const unsigned short* __restrict__ A, const unsigned short* __restrict__ Bt,
    void* __restrict__ C, int M, int N, int K, int bmw, int per_e, int nwg) {
    gemm_body<1, 4>(A, Bt, C, M, N, K, bmw, per_e, nwg);
}
__global__ __launch_bounds__(512, 2) void gemm_mlp2(
    const unsigned short* __restrict__ A, const unsigned short* __restrict__ Bt,
    void* __restrict__ C, int M, int N, int K, int bmw, int per_e, int nwg) {
    gemm_body<0, 1>(A, Bt, C, M, N, K, bmw, per_e, nwg);
}

extern "C" void kernel_launch(void* const* d_in, const int* in_sizes, int n_in,
                              void* d_out, int out_size, void* d_ws, size_t ws_size,
                              hipStream_t stream) {
    const float* x  = (const float*)d_in[0];   // [E][T][H]
    const float* w1 = (const float*)d_in[1];   // [E][H][F]
    const float* w2 = (const float*)d_in[2];   // [E][F][H]
    float* out = (float*)d_out;                // [E][T][H]

    const int E = 8, T = 2048, H = 1024, F = 4096;

    // workspace (bf16): x | w1^T | w2^T | h
    unsigned short* xb  = (unsigned short*)d_ws;
    unsigned short* w1t = xb  + (size_t)E * T * H;   // [E][F][H]
    unsigned short* w2t = w1t + (size_t)E * H * F;   // [E][H][F]
    unsigned short* hb  = w2t + (size_t)E * F * H;   // [E][T][F]

    cvt_f32_to_bf16<<<2048, 256, 0, stream>>>(x, xb, (long long)E * T * H);

    // w1 [E][H][F] -> w1t [E][F][H];  w2 [E][F][H] -> w2t [E][H][F]
    transpose_cvt64v2<<<dim3(F / 64, H / 64, E), 256, 0, stream>>>(w1, w1t, H, F);
    transpose_cvt64v2<<<dim3(H / 64, F / 64, E), 256, 0, stream>>>(w2, w2t, F, H);

    // GEMM1 + GELU: hb[e] = gelu(xb[e] @ w1[e]),  M=2048, N=4096, K=1024
    {
        int M_ = T, N_ = F, K_ = H;
        int bmw = (M_ / 256) / 4;          // 2
        int per_e = (N_ / 256) * bmw;      // 32
        int nwg = E * per_e;               // 256
        gemm_mlp1<<<nwg, 512, 0, stream>>>(xb, w1t, hb, M_, N_, K_, bmw, per_e, nwg);
    }
    // GEMM2: out[e] = hb[e] @ w2[e],  M=2048, N=1024, K=4096
    {
        int M_ = T, N_ = H, K_ = F;
        int bmw = M_ / 256;                // 8
        int per_e = (N_ / 256) * bmw;      // 32
        int nwg = E * per_e;               // 256
        gemm_mlp2<<<nwg, 512, 0, stream>>>(hb, w2t, out, M_, N_, K_, bmw, per_e, nwg);
    }
}

// Round 9
// 379.482 us; speedup vs baseline: 1.0273x; 1.0273x over previous
//
#include <hip/hip_runtime.h>
#include <hip/hip_bf16.h>

typedef __attribute__((ext_vector_type(8))) short short8;
typedef __attribute__((ext_vector_type(8))) unsigned short ushort8;
typedef __attribute__((ext_vector_type(4))) float f32x4;

typedef const __attribute__((address_space(1))) void* as1cv_t;
typedef __attribute__((address_space(3))) void* as3v_t;
typedef __attribute__((address_space(3))) const char* as3cc_t;
typedef __attribute__((address_space(3))) const short8* as3s8_t;

__device__ __forceinline__ unsigned short f2bf(float f) {
    unsigned u = __float_as_uint(f);
    u += 0x7fffu + ((u >> 16) & 1u);   // round-to-nearest-even
    return (unsigned short)(u >> 16);
}

__device__ __forceinline__ float gelu_tanh_f(float x) {
    float t = 0.7978845608028654f * (x + 0.044715f * x * x * x);
    float u = 2.0f * t;
    u = fminf(fmaxf(u, -30.0f), 30.0f);
    float e = __expf(u);
    float th = (e - 1.0f) / (e + 1.0f);
    return 0.5f * x * (1.0f + th);
}

// ---------------- merged prep: w1^T, w2^T, x-cvt in ONE dispatch ----------------
__device__ __forceinline__ void tr64body(const float* ine, unsigned short* oute,
                                         int R, int C, int c0, int r0, int t,
                                         float* LT) {
#pragma unroll
    for (int q = 0; q < 4; ++q) {
        int f = q * 256 + t;
        int lr = f >> 4;          // row 0..63
        int lc4 = f & 15;         // col-quad
        float4 v = *(const float4*)(ine + (size_t)(r0 + lr) * C + c0 + lc4 * 4);
        LT[(lc4 * 4 + 0) * 65 + lr] = v.x;
        LT[(lc4 * 4 + 1) * 65 + lr] = v.y;
        LT[(lc4 * 4 + 2) * 65 + lr] = v.z;
        LT[(lc4 * 4 + 3) * 65 + lr] = v.w;
    }
    __syncthreads();
#pragma unroll
    for (int s = 0; s < 2; ++s) {
        int oc = t >> 2;                  // out row (c) 0..63
        int or8 = (t & 3) + s * 4;        // out col-octet 0..7
        const float* src = &LT[oc * 65 + or8 * 8];
        ushort8 o;
#pragma unroll
        for (int j = 0; j < 8; ++j) o[j] = f2bf(src[j]);
        *(ushort8*)(oute + (size_t)(c0 + oc) * R + r0 + or8 * 8) = o;
    }
}

__global__ void prep_all(const float* __restrict__ x,
                         const float* __restrict__ w1,
                         const float* __restrict__ w2,
                         unsigned short* __restrict__ xb,
                         unsigned short* __restrict__ w1t,
                         unsigned short* __restrict__ w2t) {
    __shared__ float LT[64 * 65];
    const int E = 8, T = 2048, H = 1024, F = 4096;
    int bid = blockIdx.x;
    int t = threadIdx.x;
    if (bid < 8192) {
        // w1 [E][H][F] -> w1t [E][F][H]  (R=H, C=F): 64 x 16 x 8 tiles
        int cx = bid & 63, rest = bid >> 6;
        int ry = rest & 15, e = rest >> 4;
        tr64body(w1 + (size_t)e * H * F, w1t + (size_t)e * H * F,
                 H, F, cx * 64, ry * 64, t, LT);
    } else if (bid < 16384) {
        // w2 [E][F][H] -> w2t [E][H][F]  (R=F, C=H): 16 x 64 x 8 tiles
        int b = bid - 8192;
        int cx = b & 15, rest = b >> 4;
        int ry = rest & 63, e = rest >> 6;
        tr64body(w2 + (size_t)e * F * H, w2t + (size_t)e * F * H,
                 F, H, cx * 64, ry * 64, t, LT);
    } else {
        // x fp32 -> bf16, grid-stride over 2048 blocks
        int b = bid - 16384;
        long long i = (long long)b * 256 + t;
        long long stride = 2048LL * 256;
        const float4* in4 = (const float4*)x;
        ushort4* out4 = (ushort4*)xb;
        long long n4 = ((long long)E * T * H) >> 2;
        for (long long j = i; j < n4; j += stride) {
            float4 v = in4[j];
            ushort4 o;
            o.x = f2bf(v.x); o.y = f2bf(v.y); o.z = f2bf(v.z); o.w = f2bf(v.w);
            out4[j] = o;
        }
    }
}

// =======================================================================
// GEMM: r7 persistent 8-phase structure; ROUND 9 change = scheduler UNPINNED
// (no sched_barrier(0), no explicit lgkmcnt(0); compiler fences at barriers
// keep the memory/barrier ledger intact, compiler emits fine-grained waits).
// =======================================================================
__device__ __forceinline__ void gload16(const void* g, void* l) {
    __builtin_amdgcn_global_load_lds((as1cv_t)g, (as3v_t)l, 16, 0, 0);
}

#define MFMA_BF16 __builtin_amdgcn_mfma_f32_16x16x32_bf16
#define FENCE() asm volatile("" ::: "memory")

template <int DO_GELU, int ROUNDS>
__device__ __forceinline__ void gemm_body(
    const unsigned short* __restrict__ A,   // [E][M][K] bf16
    const unsigned short* __restrict__ Bt,  // [E][N][K] bf16
    void* __restrict__ Cout,                // [E][M][N] bf16 (gelu) or fp32
    int M, int N, int K, int bmw_count, int per_e, int nwg)
{
    int bid = blockIdx.x;
    int gbid = (bid & 7) * (nwg >> 3) + (bid >> 3);
    int e  = gbid / per_e;
    int t0_ = gbid % per_e;
    int bn  = t0_ / bmw_count;
    int sub = t0_ % bmw_count;
    int bm0 = sub * ROUNDS;

    const size_t K2 = (size_t)K * 2;
    const char* Ae = (const char*)A  + ((size_t)e * M * K + (size_t)bm0 * 256 * K) * 2;
    const char* Be = (const char*)Bt + ((size_t)e * N * K + (size_t)bn  * 256 * K) * 2;

    __shared__ alignas(16) unsigned short lds[2 * 32768];   // 128 KiB
    char* ldsc = (char*)lds;
    as3cc_t lb = (as3cc_t)(const char*)lds;

    int tid  = threadIdx.x;
    int wid  = tid >> 6;
    int lane = tid & 63;
    int wave_m = wid >> 2;
    int wave_n = wid & 3;

    int srow = wid * 8 + (lane >> 3);
    int kbsw = ((lane & 7) ^ (srow & 7)) << 4;
    const char* gA = Ae + (size_t)srow * K2 + kbsw;
    const char* gB = Be + (size_t)srow * K2 + kbsw;
    const size_t HROW = 64 * K2;
    const size_t HALF = 128 * K2;
    int sOff = wid << 10;

    unsigned kg   = (unsigned)(lane >> 4);
    unsigned keyl = (unsigned)((lane & 15) & 7);
    unsigned sl0  = (kg ^ keyl) << 4;
    unsigned aoff = (unsigned)(wave_m * 16384 + (lane & 15) * 128) + sl0;
    unsigned boff = 32768u + (unsigned)((wave_n >> 1) * 16384 +
                    ((wave_n & 1) * 64 + (lane & 15)) * 128) + sl0;

    f32x4 acc[8][4];
    f32x4 zero = {0.0f, 0.0f, 0.0f, 0.0f};
#pragma unroll
    for (int i = 0; i < 8; i++)
#pragma unroll
        for (int j = 0; j < 4; j++) acc[i][j] = zero;

    const int KT = K >> 6;
    const int NT_TOT = ROUNDS * KT;
    const size_t AROUND = 255 * K2;

    int kA = 0, kB = 0;
#define ADV_A() do { gA += 128; if (++kA == KT) { kA = 0; gA += AROUND; } } while (0)
#define ADV_B() do { gB += 128; if (++kB == KT) { kB = 0; gB -= K2; } } while (0)

#define STG_A(h, r, bufbit) gload16(gA + (h) * HALF + (r) * HROW, \
        ldsc + ((bufbit) << 16) + (h) * 16384 + (r) * 8192 + sOff)
#define STG_B(h, r, bufbit) gload16(gB + (h) * HALF + (r) * HROW, \
        ldsc + ((bufbit) << 16) + 32768 + (h) * 16384 + (r) * 8192 + sOff)

    STG_A(0, 0, 0); STG_A(0, 1, 0); STG_A(1, 0, 0); STG_A(1, 1, 0);
    STG_B(0, 0, 0); STG_B(0, 1, 0); STG_B(1, 0, 0); STG_B(1, 1, 0);
    ADV_B();
    if (NT_TOT > 1) {
        STG_B(0, 0, 1); STG_B(0, 1, 1); STG_B(1, 0, 1); STG_B(1, 1, 1);
        asm volatile("s_waitcnt vmcnt(4)" ::: "memory");
    } else {
        asm volatile("s_waitcnt vmcnt(0)" ::: "memory");
    }
    ADV_B();
    ADV_A();
    __builtin_amdgcn_s_barrier();
    FENCE();

    int ktEp = 0, rEp = 0;

    for (int t = 0; t < NT_TOT; ++t) {
        unsigned bufR = (unsigned)(t & 1) << 16;
        int wbA = (t + 1) & 1;
        int wbB = t & 1;
        bool stA = (t + 1) < NT_TOT;
        bool stB = (t + 2) < NT_TOT;

        unsigned pa0 = bufR + aoff, pa1 = pa0 ^ 64u;
        unsigned pb0 = bufR + boff, pb1 = pb0 ^ 64u;

        short8 aL[4][2], aH[4][2], bL[2][2], bH[2][2];

        // phase 1: read A[m0-3] + B[n0-1]; stage A0(t+1)
#pragma unroll
        for (int mi = 0; mi < 4; ++mi) {
            aL[mi][0] = *(as3s8_t)(lb + (pa0 + mi * 2048));
            aL[mi][1] = *(as3s8_t)(lb + (pa1 + mi * 2048));
        }
#pragma unroll
        for (int ni = 0; ni < 2; ++ni) {
            bL[ni][0] = *(as3s8_t)(lb + (pb0 + ni * 2048));
            bL[ni][1] = *(as3s8_t)(lb + (pb1 + ni * 2048));
        }
        if (stA) { STG_A(0, 0, wbA); STG_A(0, 1, wbA); }
        FENCE();
        __builtin_amdgcn_s_barrier();
        FENCE();
        __builtin_amdgcn_s_setprio(1);
#pragma unroll
        for (int ks = 0; ks < 2; ++ks)
#pragma unroll
            for (int mi = 0; mi < 4; ++mi)
#pragma unroll
                for (int ni = 0; ni < 2; ++ni)
                    acc[mi][ni] = MFMA_BF16(aL[mi][ks], bL[ni][ks], acc[mi][ni], 0, 0, 0);
        __builtin_amdgcn_s_setprio(0);
        FENCE();
        __builtin_amdgcn_s_barrier();
        FENCE();

        // phase 2: read B[n2-3]; stage A1(t+1); advance A
#pragma unroll
        for (int ni = 0; ni < 2; ++ni) {
            bH[ni][0] = *(as3s8_t)(lb + (pb0 + (2 + ni) * 2048));
            bH[ni][1] = *(as3s8_t)(lb + (pb1 + (2 + ni) * 2048));
        }
        if (stA) { STG_A(1, 0, wbA); STG_A(1, 1, wbA); }
        ADV_A();
        FENCE();
        __builtin_amdgcn_s_barrier();
        FENCE();
        __builtin_amdgcn_s_setprio(1);
#pragma unroll
        for (int ks = 0; ks < 2; ++ks)
#pragma unroll
            for (int mi = 0; mi < 4; ++mi)
#pragma unroll
                for (int ni = 0; ni < 2; ++ni)
                    acc[mi][2 + ni] = MFMA_BF16(aL[mi][ks], bH[ni][ks], acc[mi][2 + ni], 0, 0, 0);
        __builtin_amdgcn_s_setprio(0);
        FENCE();
        __builtin_amdgcn_s_barrier();
        FENCE();

        // phase 3: read A[m4-7]; stage B0(t+2)
#pragma unroll
        for (int mi = 0; mi < 4; ++mi) {
            aH[mi][0] = *(as3s8_t)(lb + (pa0 + (4 + mi) * 2048));
            aH[mi][1] = *(as3s8_t)(lb + (pa1 + (4 + mi) * 2048));
        }
        if (stB) { STG_B(0, 0, wbB); STG_B(0, 1, wbB); }
        FENCE();
        __builtin_amdgcn_s_barrier();
        FENCE();
        __builtin_amdgcn_s_setprio(1);
#pragma unroll
        for (int ks = 0; ks < 2; ++ks)
#pragma unroll
            for (int mi = 0; mi < 4; ++mi)
#pragma unroll
                for (int ni = 0; ni < 2; ++ni)
                    acc[4 + mi][2 + ni] = MFMA_BF16(aH[mi][ks], bH[ni][ks], acc[4 + mi][2 + ni], 0, 0, 0);
        __builtin_amdgcn_s_setprio(0);
        FENCE();
        __builtin_amdgcn_s_barrier();
        FENCE();

        // phase 4: stage B1(t+2); advance B; ONE counted vmcnt
        // ledger: [B(t+1):4 | A(t+1):4 | B(t+2):4] -> vmcnt(4) retires tile t+1
        if (stB) { STG_B(1, 0, wbB); STG_B(1, 1, wbB); }
        ADV_B();
        if (stB) asm volatile("s_waitcnt vmcnt(4)" ::: "memory");
        else     asm volatile("s_waitcnt vmcnt(0)" ::: "memory");
        __builtin_amdgcn_s_barrier();
        FENCE();
        __builtin_amdgcn_s_setprio(1);
#pragma unroll
        for (int ks = 0; ks < 2; ++ks)
#pragma unroll
            for (int mi = 0; mi < 4; ++mi)
#pragma unroll
                for (int ni = 0; ni < 2; ++ni)
                    acc[4 + mi][ni] = MFMA_BF16(aH[mi][ks], bL[ni][ks], acc[4 + mi][ni], 0, 0, 0);
        __builtin_amdgcn_s_setprio(0);
        FENCE();
        __builtin_amdgcn_s_barrier();
        FENCE();

        // per-round epilogue (prefetch stays in flight across it)
        if (++ktEp == KT) {
            ktEp = 0;
            int row0 = (bm0 + rEp) * 256 + wave_m * 128 + ((lane >> 4) << 2);
            int col0 = bn * 256 + wave_n * 64 + (lane & 15);
            if (DO_GELU) {
                unsigned short* Ce = (unsigned short*)Cout + (size_t)e * M * N;
#pragma unroll
                for (int m = 0; m < 8; ++m)
#pragma unroll
                    for (int n = 0; n < 4; ++n)
#pragma unroll
                        for (int j = 0; j < 4; ++j) {
                            int row = row0 + m * 16 + j;
                            int col = col0 + n * 16;
                            Ce[(size_t)row * N + col] = f2bf(gelu_tanh_f(acc[m][n][j]));
                        }
            } else {
                float* Ce = (float*)Cout + (size_t)e * M * N;
#pragma unroll
                for (int m = 0; m < 8; ++m)
#pragma unroll
                    for (int n = 0; n < 4; ++n)
#pragma unroll
                        for (int j = 0; j < 4; ++j) {
                            int row = row0 + m * 16 + j;
                            int col = col0 + n * 16;
                            Ce[(size_t)row * N + col] = acc[m][n][j];
                        }
            }
            rEp++;
#pragma unroll
            for (int i = 0; i < 8; i++)
#pragma unroll
                for (int j = 0; j < 4; j++) acc[i][j] = zero;
        }
    }
#undef STG_A
#undef STG_B
#undef ADV_A
#undef ADV_B
}

__global__ __launch_bounds__(512, 2) void gemm_mlp1(
    const unsigned short* __restrict__ A, const unsigned short* __restrict__ Bt,
    void* __restrict__ C, int M, int N, int K, int bmw, int per_e, int nwg) {
    gemm_body<1, 4>(A, Bt, C, M, N, K, bmw, per_e, nwg);
}
__global__ __launch_bounds__(512, 2) void gemm_mlp2(
    const unsigned short* __restrict__ A, const unsigned short* __restrict__ Bt,
    void* __restrict__ C, int M, int N, int K, int bmw, int per_e, int nwg) {
    gemm_body<0, 1>(A, Bt, C, M, N, K, bmw, per_e, nwg);
}

extern "C" void kernel_launch(void* const* d_in, const int* in_sizes, int n_in,
                              void* d_out, int out_size, void* d_ws, size_t ws_size,
                              hipStream_t stream) {
    const float* x  = (const float*)d_in[0];   // [E][T][H]
    const float* w1 = (const float*)d_in[1];   // [E][H][F]
    const float* w2 = (const float*)d_in[2];   // [E][F][H]
    float* out = (float*)d_out;                // [E][T][H]

    const int E = 8, T = 2048, H = 1024, F = 4096;

    // workspace (bf16): x | w1^T | w2^T | h
    unsigned short* xb  = (unsigned short*)d_ws;
    unsigned short* w1t = xb  + (size_t)E * T * H;   // [E][F][H]
    unsigned short* w2t = w1t + (size_t)E * H * F;   // [E][H][F]
    unsigned short* hb  = w2t + (size_t)E * F * H;   // [E][T][F]

    // ONE prep dispatch: 8192 (w1t) + 8192 (w2t) + 2048 (x-cvt) blocks
    prep_all<<<18432, 256, 0, stream>>>(x, w1, w2, xb, w1t, w2t);

    // GEMM1 + GELU: hb[e] = gelu(xb[e] @ w1[e]),  M=2048, N=4096, K=1024
    {
        int M_ = T, N_ = F, K_ = H;
        int bmw = (M_ / 256) / 4;          // 2
        int per_e = (N_ / 256) * bmw;      // 32
        int nwg = E * per_e;               // 256
        gemm_mlp1<<<nwg, 512, 0, stream>>>(xb, w1t, hb, M_, N_, K_, bmw, per_e, nwg);
    }
    // GEMM2: out[e] = hb[e] @ w2[e],  M=2048, N=1024, K=4096
    {
        int M_ = T, N_ = H, K_ = F;
        int bmw = M_ / 256;                // 8
        int per_e = (N_ / 256) * bmw;      // 32
        int nwg = E * per_e;               // 256
        gemm_mlp2<<<nwg, 512, 0, stream>>>(hb, w2t, out, M_, N_, K_, bmw, per_e, nwg);
    }
}